// Round 1
// 279.673 us; speedup vs baseline: 1.0275x; 1.0275x over previous
//
#include <hip/hip_runtime.h>
#include <math.h>

#define N_NODES 50000
#define N_EDGES 800000
#define ET (N_EDGES + N_NODES)   // with self-loops
#define FDIM 128
#define HEADS 4
#define HID 32
#define NCLS 8
#define NEG 0.2f
#define EPS_BN 1e-5f

#define BSH 6                                   // 64 nodes per bucket
#define NBUCK ((N_NODES + 63) >> BSH)           // 782
#define EPB 4096                                // edges per partition block

typedef __attribute__((ext_vector_type(8))) short short8;
typedef __attribute__((ext_vector_type(4))) float f32x4;

__device__ __forceinline__ float lrelu(float e) { return e > 0.f ? e : NEG * e; }
__device__ __forceinline__ float bflo(unsigned u) { return __uint_as_float(u << 16); }
__device__ __forceinline__ float bfhi(unsigned u) { return __uint_as_float(u & 0xffff0000u); }
__device__ __forceinline__ unsigned f2bf(float f) {           // RNE round to bf16 bits
    unsigned b = __float_as_uint(f);
    return (b + 0x7fffu + ((b >> 16) & 1u)) >> 16;
}

// exclusive scan of bhist[NBUCK] into bloc[NBUCK] using stmp[256]; all 256 threads.
__device__ __forceinline__ void scan_bhist(const int* __restrict__ bhist,
                                           int* bloc, int* stmp) {
    int t = threadIdx.x;
    int idx = t * 4;
    int v0 = (idx     < NBUCK) ? bhist[idx]     : 0;
    int v1 = (idx + 1 < NBUCK) ? bhist[idx + 1] : 0;
    int v2 = (idx + 2 < NBUCK) ? bhist[idx + 2] : 0;
    int v3 = (idx + 3 < NBUCK) ? bhist[idx + 3] : 0;
    int sum = v0 + v1 + v2 + v3;
    stmp[t] = sum;
    __syncthreads();
    for (int off = 1; off < 256; off <<= 1) {
        int x = (t >= off) ? stmp[t - off] : 0;
        __syncthreads();
        stmp[t] += x;
        __syncthreads();
    }
    int run = stmp[t] - sum;
    if (idx     < NBUCK) bloc[idx]     = run; run += v0;
    if (idx + 1 < NBUCK) bloc[idx + 1] = run; run += v1;
    if (idx + 2 < NBUCK) bloc[idx + 2] = run; run += v2;
    if (idx + 3 < NBUCK) bloc[idx + 3] = run;
    __syncthreads();
}

// ---------------- fused K1: x->bf16 cast + W0/W1 fragment packing + bucket histogram ----------------

#define CAST_B 3125   // 50000*128/8/256
#define PACK_B 64     // 16384/256
#define PB ((ET + EPB - 1) / EPB)   // 208

__global__ __launch_bounds__(256) void prep_hist(
        const float* __restrict__ x, unsigned short* __restrict__ xb,
        const float* __restrict__ W0, unsigned short* __restrict__ W0p,
        const float* __restrict__ W1, unsigned short* __restrict__ W1p,
        const int* __restrict__ ei, int* __restrict__ bhist) {
    __shared__ unsigned h[NBUCK];
    int b = blockIdx.x, tid = threadIdx.x;
    if (b < CAST_B) {
        int i = b * 256 + tid;
        const float4* p = (const float4*)x + (size_t)i * 2;
        float4 a = p[0], c = p[1];
        uint4 o;
        o.x = f2bf(a.x) | (f2bf(a.y) << 16);
        o.y = f2bf(a.z) | (f2bf(a.w) << 16);
        o.z = f2bf(c.x) | (f2bf(c.y) << 16);
        o.w = f2bf(c.z) | (f2bf(c.w) << 16);
        ((uint4*)xb)[i] = o;
    } else if (b < CAST_B + 2 * PACK_B) {
        int pb = b - CAST_B;
        const float* W = (pb < PACK_B) ? W0 : W1;
        unsigned short* Wp = (pb < PACK_B) ? W0p : W1p;
        int o = (pb & (PACK_B - 1)) * 256 + tid;
        int j = o & 7, lane = (o >> 3) & 63, kc = (o >> 9) & 3, t = o >> 11;
        int k = kc * 32 + ((lane >> 4) << 3) + j;
        int n = t * 16 + (lane & 15);
        Wp[o] = (unsigned short)f2bf(W[k * 128 + n]);
    } else {
        int blk = b - (CAST_B + 2 * PACK_B);
        int e0 = blk * EPB;
        for (int i = tid; i < NBUCK; i += 256) h[i] = 0;
        __syncthreads();
        #pragma unroll
        for (int k = 0; k < EPB / 256; k++) {
            int e = e0 + k * 256 + tid;
            if (e < ET) {
                int d = (e < N_EDGES) ? ei[N_EDGES + e] : (e - N_EDGES);
                atomicAdd(&h[d >> BSH], 1u);
            }
        }
        __syncthreads();
        for (int i = tid; i < NBUCK; i += 256)
            if (h[i]) atomicAdd(&bhist[i], (int)h[i]);
    }
}

// ------- shared gemm body: fused MFMA GEMM (64 x 128 @ 128 x 128) + bf16 h-store + attn coeffs -------

__device__ __forceinline__ void gemm_attn_body(
        float* tiles, int gb,
        const unsigned short* __restrict__ Ab, const unsigned short* __restrict__ Wp,
        const float* __restrict__ att_s, const float* __restrict__ att_d,
        unsigned short* __restrict__ Hb, float* __restrict__ asn, float* __restrict__ adn,
        int M) {
    int tid = threadIdx.x;
    int wv = tid >> 6, lane = tid & 63;
    int base = gb * 64;
    int mrow = base + wv * 16 + (lane & 15);
    if (mrow >= M) mrow = M - 1;
    int koff = (lane >> 4) * 8;

    f32x4 acc[8];
    #pragma unroll
    for (int t = 0; t < 8; t++) acc[t] = (f32x4){0.f, 0.f, 0.f, 0.f};

    #pragma unroll
    for (int kc = 0; kc < 4; kc++) {
        short8 a = *(const short8*)(Ab + (size_t)mrow * 128 + kc * 32 + koff);
        #pragma unroll
        for (int t = 0; t < 8; t++) {
            short8 bfr = *(const short8*)(Wp + (((t * 4 + kc) * 64 + lane) << 3));
            acc[t] = __builtin_amdgcn_mfma_f32_16x16x32_bf16(a, bfr, acc[t], 0, 0, 0);
        }
    }

    int rbase = wv * 16 + (lane >> 4) * 4;
    int col = lane & 15;
    #pragma unroll
    for (int t = 0; t < 8; t++)
        #pragma unroll
        for (int r = 0; r < 4; r++)
            tiles[(rbase + r) * 132 + t * 16 + col] = acc[t][r];
    __syncthreads();

    #pragma unroll
    for (int it = 0; it < 4; it++) {
        int u = tid + it * 256;
        int rl = u >> 4, cg = u & 15;
        int row = base + rl;
        if (row < M) {
            const float* p = tiles + rl * 132 + cg * 8;
            float4 v0 = *(const float4*)(p);
            float4 v1 = *(const float4*)(p + 4);
            uint4 o;
            o.x = f2bf(v0.x) | (f2bf(v0.y) << 16);
            o.y = f2bf(v0.z) | (f2bf(v0.w) << 16);
            o.z = f2bf(v1.x) | (f2bf(v1.y) << 16);
            o.w = f2bf(v1.z) | (f2bf(v1.w) << 16);
            *(uint4*)(Hb + (size_t)row * 128 + cg * 8) = o;
        }
    }

    {
        int rl = tid >> 2, hd = tid & 3;
        int row = base + rl;
        if (row < M) {
            const float* hrow = tiles + rl * 132 + hd * 32;
            const float* as = att_s + hd * 32;
            const float* ad = att_d + hd * 32;
            float ps = 0.f, pd = 0.f;
            #pragma unroll
            for (int i = 0; i < 8; i++) {
                float4 hv = *(const float4*)(hrow + i * 4);
                float4 sv = *(const float4*)(as + i * 4);
                float4 dv = *(const float4*)(ad + i * 4);
                ps += hv.x * sv.x + hv.y * sv.y + hv.z * sv.z + hv.w * sv.w;
                pd += hv.x * dv.x + hv.y * dv.y + hv.z * dv.z + hv.w * dv.w;
            }
            asn[row * 4 + hd] = ps;
            adn[row * 4 + hd] = pd;
        }
    }
}

// ---------------- fused K2: radix partition (blocks [0,PB)) + layer-0 GEMM (blocks [PB,PB+GB)) ----------------

__global__ __launch_bounds__(256) void part_gemm(
        const int* __restrict__ ei, const int* __restrict__ bhist,
        int* __restrict__ bcur, int2* __restrict__ pairs,
        const unsigned short* __restrict__ Ab, const unsigned short* __restrict__ Wp,
        const float* __restrict__ att_s, const float* __restrict__ att_d,
        unsigned short* __restrict__ Hb, float* __restrict__ asn, float* __restrict__ adn,
        int M) {
    __shared__ float smem[64 * 132];    // 33792 B; partition path aliases ints inside
    int tid = threadIdx.x;
    if (blockIdx.x < PB) {
        unsigned* hist = (unsigned*)smem;             // NBUCK
        unsigned* base = hist + NBUCK;                // NBUCK
        int* bloc = (int*)(base + NBUCK);             // NBUCK
        int* stmp = bloc + NBUCK;                     // 256
        for (int i = tid; i < NBUCK; i += 256) hist[i] = 0;
        scan_bhist(bhist, bloc, stmp);                // barriers inside
        int e0 = blockIdx.x * EPB;
        #pragma unroll
        for (int k = 0; k < EPB / 256; k++) {
            int e = e0 + k * 256 + tid;
            if (e < ET) {
                int d = (e < N_EDGES) ? ei[N_EDGES + e] : (e - N_EDGES);
                atomicAdd(&hist[d >> BSH], 1u);
            }
        }
        __syncthreads();
        for (int i = tid; i < NBUCK; i += 256) {
            unsigned h = hist[i];
            base[i] = h ? (unsigned)(bloc[i] + atomicAdd(&bcur[i], (int)h)) : 0u;
            hist[i] = 0;
        }
        __syncthreads();
        #pragma unroll
        for (int k = 0; k < EPB / 256; k++) {
            int e = e0 + k * 256 + tid;
            if (e < ET) {
                int s, d;
                if (e < N_EDGES) { s = ei[e]; d = ei[N_EDGES + e]; }
                else             { s = d = e - N_EDGES; }
                int bk = d >> BSH;
                unsigned lpos = atomicAdd(&hist[bk], 1u);
                pairs[base[bk] + lpos] = make_int2(s, d);
            }
        }
    } else {
        gemm_attn_body(smem, blockIdx.x - PB, Ab, Wp, att_s, att_d, Hb, asn, adn, M);
    }
}

// standalone GEMM kernel for layer 1
__global__ __launch_bounds__(256) void gemm_attn(
        const unsigned short* __restrict__ Ab, const unsigned short* __restrict__ Wp,
        const float* __restrict__ att_s, const float* __restrict__ att_d,
        unsigned short* __restrict__ Hb, float* __restrict__ asn, float* __restrict__ adn,
        int M) {
    __shared__ float tiles[64 * 132];
    gemm_attn_body(tiles, blockIdx.x, Ab, Wp, att_s, att_d, Hb, asn, adn, M);
}

// ---------------- K3: per bucket (64 nodes), per-node offsets + regroup pairs -> ssrc ----------------

__global__ __launch_bounds__(256) void group_bucket(const int2* __restrict__ pairs,
                                                    const int* __restrict__ bhist,
                                                    int* __restrict__ offs,
                                                    int* __restrict__ ssrc) {
    __shared__ int bloc[NBUCK];
    __shared__ int stmp[256];
    __shared__ int cnt[64];
    int b = blockIdx.x, tid = threadIdx.x;
    scan_bhist(bhist, bloc, stmp);
    int base = bloc[b];
    int end = (b + 1 < NBUCK) ? bloc[b + 1] : ET;
    int n0 = b << BSH;
    if (tid < 64) cnt[tid] = 0;
    __syncthreads();
    for (int i = base + tid; i < end; i += 256)
        atomicAdd(&cnt[pairs[i].y & 63], 1);
    __syncthreads();
    int v = (tid < 64) ? cnt[tid] : 0;
    stmp[tid] = v;
    __syncthreads();
    for (int off = 1; off < 64; off <<= 1) {
        int x = (tid >= off) ? stmp[tid - off] : 0;
        __syncthreads();
        stmp[tid] += x;
        __syncthreads();
    }
    int excl = stmp[tid] - v;
    if (tid < 64) {
        if (n0 + tid < N_NODES) offs[n0 + tid] = base + excl;
        cnt[tid] = excl;                 // reuse as cursor
    }
    __syncthreads();
    for (int i = base + tid; i < end; i += 256) {
        int2 p = pairs[i];
        int pos = atomicAdd(&cnt[p.y & 63], 1);
        ssrc[base + pos] = p.x;
    }
    if (b == 0 && tid == 0) offs[N_NODES] = ET;
}

// ------- aggregation + bias + BN + ELU (layers 0,1): one wave/node, channel-parallel -------
// No max-subtraction: logits are bounded (|e| ~ O(10)) so exp(e)/sum(exp(e)) is safe and
// mathematically identical to the stabilized form. Single edge sweep + phase C.

__global__ __launch_bounds__(256) void aggregate(
        const unsigned short* __restrict__ hb, const float* __restrict__ asn,
        const float* __restrict__ adn, const int* __restrict__ offs,
        const int* __restrict__ ssrc, const float* __restrict__ bias,
        const float* __restrict__ gamma, const float* __restrict__ beta,
        const float* __restrict__ rmean, const float* __restrict__ rvar,
        unsigned short* __restrict__ outb) {
    __shared__ int2 sPair[4][4][72];   // [wave][head][slot]; stride 72 -> heads offset 16 banks
    int wv = threadIdx.x >> 6;
    int node = blockIdx.x * 4 + wv;
    if (node >= N_NODES) return;
    int lane = threadIdx.x & 63;
    int hd = lane >> 4;
    int beg = offs[node], deg = offs[node + 1] - beg;
    float4 ad4 = *(const float4*)(adn + node * 4);

    if (lane < 32) sPair[wv][lane >> 3][64 + (lane & 7)] = make_int2(0, 0);

    float4 den4 = make_float4(0.f, 0.f, 0.f, 0.f);
    float acc0 = 0.f, acc1 = 0.f;
    const unsigned short* hlane = hb + 2 * lane;
    const int2* pp = &sPair[wv][hd][0];

    auto phaseC = [&](int cnt) {
        int bound = (cnt + 7) & ~7;
        for (int i = 0; i < bound; i += 8) {
            int2 p0 = pp[i],     p1 = pp[i + 1], p2 = pp[i + 2], p3 = pp[i + 3];
            int2 p4 = pp[i + 4], p5 = pp[i + 5], p6 = pp[i + 6], p7 = pp[i + 7];
            unsigned u0 = *(const unsigned*)(hlane + (((unsigned)p0.x) << 7));
            unsigned u1 = *(const unsigned*)(hlane + (((unsigned)p1.x) << 7));
            unsigned u2 = *(const unsigned*)(hlane + (((unsigned)p2.x) << 7));
            unsigned u3 = *(const unsigned*)(hlane + (((unsigned)p3.x) << 7));
            unsigned u4 = *(const unsigned*)(hlane + (((unsigned)p4.x) << 7));
            unsigned u5 = *(const unsigned*)(hlane + (((unsigned)p5.x) << 7));
            unsigned u6 = *(const unsigned*)(hlane + (((unsigned)p6.x) << 7));
            unsigned u7 = *(const unsigned*)(hlane + (((unsigned)p7.x) << 7));
            acc0 += __int_as_float(p0.y) * bflo(u0); acc1 += __int_as_float(p0.y) * bfhi(u0);
            acc0 += __int_as_float(p1.y) * bflo(u1); acc1 += __int_as_float(p1.y) * bfhi(u1);
            acc0 += __int_as_float(p2.y) * bflo(u2); acc1 += __int_as_float(p2.y) * bfhi(u2);
            acc0 += __int_as_float(p3.y) * bflo(u3); acc1 += __int_as_float(p3.y) * bfhi(u3);
            acc0 += __int_as_float(p4.y) * bflo(u4); acc1 += __int_as_float(p4.y) * bfhi(u4);
            acc0 += __int_as_float(p5.y) * bflo(u5); acc1 += __int_as_float(p5.y) * bfhi(u5);
            acc0 += __int_as_float(p6.y) * bflo(u6); acc1 += __int_as_float(p6.y) * bfhi(u6);
            acc0 += __int_as_float(p7.y) * bflo(u7); acc1 += __int_as_float(p7.y) * bfhi(u7);
        }
    };

    for (int base0 = 0; base0 < deg; base0 += 64) {
        int j = base0 + lane;
        int s = 0;
        float4 w4 = make_float4(0.f, 0.f, 0.f, 0.f);
        if (j < deg) {
            s = ssrc[beg + j];
            float4 a = *(const float4*)(asn + s * 4);
            w4.x = __expf(lrelu(a.x + ad4.x));
            w4.y = __expf(lrelu(a.y + ad4.y));
            w4.z = __expf(lrelu(a.z + ad4.z));
            w4.w = __expf(lrelu(a.w + ad4.w));
            den4.x += w4.x; den4.y += w4.y; den4.z += w4.z; den4.w += w4.w;
        }
        sPair[wv][0][lane] = make_int2(s, __float_as_int(w4.x));
        sPair[wv][1][lane] = make_int2(s, __float_as_int(w4.y));
        sPair[wv][2][lane] = make_int2(s, __float_as_int(w4.z));
        sPair[wv][3][lane] = make_int2(s, __float_as_int(w4.w));
        int cnt = deg - base0; if (cnt > 64) cnt = 64;
        phaseC(cnt);
    }

    #pragma unroll
    for (int off = 32; off; off >>= 1) {
        den4.x += __shfl_xor(den4.x, off);
        den4.y += __shfl_xor(den4.y, off);
        den4.z += __shfl_xor(den4.z, off);
        den4.w += __shfl_xor(den4.w, off);
    }
    float den = (hd & 2) ? ((hd & 1) ? den4.w : den4.z)
                         : ((hd & 1) ? den4.y : den4.x);
    float inv = 1.f / (den + 1e-16f);

    int c0 = lane * 2;
    float2 bi = *(const float2*)(bias + c0);
    float2 gm = *(const float2*)(gamma + c0);
    float2 bt = *(const float2*)(beta + c0);
    float2 rm = *(const float2*)(rmean + c0);
    float2 rv = *(const float2*)(rvar + c0);
    float o0 = acc0 * inv + bi.x;
    float o1 = acc1 * inv + bi.y;
    o0 = (o0 - rm.x) * rsqrtf(rv.x + EPS_BN) * gm.x + bt.x;
    o1 = (o1 - rm.y) * rsqrtf(rv.y + EPS_BN) * gm.y + bt.y;
    o0 = (o0 > 0.f) ? o0 : expm1f(o0);
    o1 = (o1 > 0.f) ? o1 : expm1f(o1);
    *(unsigned*)(outb + (size_t)node * 128 + c0) = f2bf(o0) | (f2bf(o1) << 16);
}

// ---------------- layer 2: fused GEMM(128->8) + attn coeffs (bf16 input) ----------------

__global__ __launch_bounds__(256) void gemm2_fused(
        const unsigned short* __restrict__ xb, const float* __restrict__ W2,
        const float* __restrict__ as2, const float* __restrict__ ad2,
        float* __restrict__ h2, float* __restrict__ asn, float* __restrict__ adn) {
    __shared__ float sW[128 * 8];
    __shared__ float sas[8], sad[8];
    int tid = threadIdx.x;
    for (int i = tid; i < 1024; i += 256) sW[i] = W2[i];
    if (tid < 8) { sas[tid] = as2[tid]; sad[tid] = ad2[tid]; }
    __syncthreads();
    int node = blockIdx.x * 256 + tid;
    if (node >= N_NODES) return;
    const uint4* xr = (const uint4*)(xb + (size_t)node * 128);
    float acc[8];
    #pragma unroll
    for (int c = 0; c < 8; c++) acc[c] = 0.f;
    for (int k8 = 0; k8 < 16; k8++) {
        uint4 u = xr[k8];
        float f[8] = { bflo(u.x), bfhi(u.x), bflo(u.y), bfhi(u.y),
                       bflo(u.z), bfhi(u.z), bflo(u.w), bfhi(u.w) };
        int kb = k8 * 8;
        #pragma unroll
        for (int q = 0; q < 8; q++)
            #pragma unroll
            for (int c = 0; c < 8; c++)
                acc[c] += f[q] * sW[(kb + q) * 8 + c];
    }
    float ps = 0.f, pd = 0.f;
    #pragma unroll
    for (int c = 0; c < 8; c++) {
        h2[(size_t)node * 8 + c] = acc[c];
        ps += acc[c] * sas[c];
        pd += acc[c] * sad[c];
    }
    asn[node] = ps;
    adn[node] = pd;
}

// ------- layer 2 aggregation + bias + log_softmax: one wave/node (no max pass) -------

__global__ __launch_bounds__(256) void aggregate2(
        const float* __restrict__ h2, const float* __restrict__ asn,
        const float* __restrict__ adn, const int* __restrict__ offs,
        const int* __restrict__ ssrc, const float* __restrict__ b2,
        float* __restrict__ out) {
    __shared__ int2 sPair[4][64];
    int wv = threadIdx.x >> 6;
    int node = blockIdx.x * 4 + wv;
    if (node >= N_NODES) return;
    int lane = threadIdx.x & 63;
    int g = lane >> 3, c = lane & 7;
    int beg = offs[node], end = offs[node + 1];
    int deg = end - beg;
    float adv = adn[node];

    float den = 0.f, acc = 0.f;
    auto phaseC = [&](int cnt) {
        int nIt = (cnt + 15) >> 4;
        const int2* pp = &sPair[wv][0];
        for (int i = 0; i < nIt; i++) {
            int e = i * 16 + g;
            int2 p0 = pp[e];
            int2 p1 = pp[e + 8];
            acc += __int_as_float(p0.y) * h2[(((unsigned)p0.x) << 3) + c];
            acc += __int_as_float(p1.y) * h2[(((unsigned)p1.x) << 3) + c];
        }
    };

    for (int base = 0; base < deg; base += 64) {
        int j = base + lane;
        int s = 0; float w = 0.f;
        if (j < deg) {
            s = ssrc[beg + j];
            w = __expf(lrelu(asn[s] + adv));
            den += w;
        }
        sPair[wv][lane] = make_int2(s, __float_as_int(w));
        int cnt = deg - base; if (cnt > 64) cnt = 64;
        phaseC(cnt);
    }

    acc += __shfl_xor(acc, 8); acc += __shfl_xor(acc, 16); acc += __shfl_xor(acc, 32);
    #pragma unroll
    for (int off = 32; off; off >>= 1) den += __shfl_xor(den, off);

    float o = acc / (den + 1e-16f) + b2[c];
    float mx = o;
    mx = fmaxf(mx, __shfl_xor(mx, 1));
    mx = fmaxf(mx, __shfl_xor(mx, 2));
    mx = fmaxf(mx, __shfl_xor(mx, 4));
    float ex = __expf(o - mx);
    float sm = ex;
    sm += __shfl_xor(sm, 1); sm += __shfl_xor(sm, 2); sm += __shfl_xor(sm, 4);
    if (g == 0) out[(size_t)node * 8 + c] = o - mx - logf(sm);
}

// ---------------- launch ----------------

extern "C" void kernel_launch(void* const* d_in, const int* in_sizes, int n_in,
                              void* d_out, int out_size, void* d_ws, size_t ws_size,
                              hipStream_t stream) {
    const float* x   = (const float*)d_in[0];
    const int*   ei  = (const int*)d_in[1];
    const float* W0  = (const float*)d_in[2];
    const float* as0 = (const float*)d_in[3];
    const float* ad0 = (const float*)d_in[4];
    const float* b0  = (const float*)d_in[5];
    const float* g0  = (const float*)d_in[6];
    const float* bb0 = (const float*)d_in[7];
    const float* rm0 = (const float*)d_in[8];
    const float* rv0 = (const float*)d_in[9];
    const float* W1  = (const float*)d_in[10];
    const float* as1 = (const float*)d_in[11];
    const float* ad1 = (const float*)d_in[12];
    const float* b1  = (const float*)d_in[13];
    const float* g1  = (const float*)d_in[14];
    const float* bb1 = (const float*)d_in[15];
    const float* rm1 = (const float*)d_in[16];
    const float* rv1 = (const float*)d_in[17];
    const float* W2  = (const float*)d_in[18];
    const float* as2 = (const float*)d_in[19];
    const float* ad2 = (const float*)d_in[20];
    const float* b2  = (const float*)d_in[21];
    float* out = (float*)d_out;

    char* w = (char*)d_ws;
    size_t off = 0;
    auto carve = [&](size_t bytes) {
        void* p = w + off;
        off += (bytes + 255) & ~(size_t)255;
        return p;
    };
    unsigned short* xb   = (unsigned short*)carve((size_t)N_NODES * 128 * 2);
    unsigned short* Hb   = (unsigned short*)carve((size_t)N_NODES * 128 * 2);
    unsigned short* Xb   = (unsigned short*)carve((size_t)N_NODES * 128 * 2);
    unsigned short* W0p  = (unsigned short*)carve(16384 * 2);
    unsigned short* W1p  = (unsigned short*)carve(16384 * 2);
    int*   offs   = (int*)carve((size_t)(N_NODES + 1) * 4);
    int*   bhist  = (int*)carve((size_t)NBUCK * 2 * 4);   // bhist + bcur (one memset)
    int*   bcur   = bhist + NBUCK;
    int*   ssrc   = (int*)carve((size_t)ET * 4);
    int2*  pairs  = (int2*)carve((size_t)ET * 8);
    float* asn    = (float*)carve((size_t)N_NODES * 4 * 4);
    float* adn    = (float*)carve((size_t)N_NODES * 4 * 4);
    float* h2     = (float*)carve((size_t)N_NODES * 8 * 4);
    float* as2n   = (float*)carve((size_t)N_NODES * 4);
    float* ad2n   = (float*)carve((size_t)N_NODES * 4);
    (void)ws_size; (void)in_sizes; (void)n_in; (void)out_size;

    const int NB = (N_NODES + 255) / 256;
    const int GB = (N_NODES + 63) / 64;

    hipMemsetAsync(bhist, 0, (size_t)NBUCK * 2 * 4, stream);
    // K1: cast + weight-pack + bucket histogram (independent work fused)
    prep_hist<<<CAST_B + 2 * PACK_B + PB, 256, 0, stream>>>(x, xb, W0, W0p, W1, W1p, ei, bhist);
    // K2: radix partition (needs bhist) || layer-0 GEMM (needs xb/W0p) — fused, overlap
    part_gemm<<<PB + GB, 256, 0, stream>>>(ei, bhist, bcur, pairs,
                                           xb, W0p, as0, ad0, Hb, asn, adn, N_NODES);
    // K3: per-bucket grouping (64-node buckets -> 782 blocks)
    group_bucket<<<NBUCK, 256, 0, stream>>>(pairs, bhist, offs, ssrc);

    aggregate<<<(N_NODES + 3) / 4, 256, 0, stream>>>(Hb, asn, adn, offs, ssrc,
                                                     b0, g0, bb0, rm0, rv0, Xb);
    gemm_attn<<<GB, 256, 0, stream>>>(Xb, W1p, as1, ad1, Hb, asn, adn, N_NODES);
    aggregate<<<(N_NODES + 3) / 4, 256, 0, stream>>>(Hb, asn, adn, offs, ssrc,
                                                     b1, g1, bb1, rm1, rv1, Xb);
    gemm2_fused<<<NB, 256, 0, stream>>>(Xb, W2, as2, ad2, h2, as2n, ad2n);
    aggregate2<<<(N_NODES + 3) / 4, 256, 0, stream>>>(h2, as2n, ad2n, offs, ssrc, b2, out);
}